// Round 1
// baseline (324.828 us; speedup 1.0000x reference)
//
#include <hip/hip_runtime.h>
#include <cstdint>
#include <cstddef>

#define NN 8192
#define DD 256

typedef __bf16 bf16x8 __attribute__((ext_vector_type(8)));
typedef float f32x4 __attribute__((ext_vector_type(4)));

// ---------------- prep: fp32 -> bf16 (RNE) + row sum-of-squares ----------------
__global__ __launch_bounds__(256) void prep_kernel(const float* __restrict__ x,
                                                   unsigned short* __restrict__ xb,
                                                   float* __restrict__ sq) {
    const int row = blockIdx.x;
    const int c = threadIdx.x;           // 256 threads = D columns
    const size_t idx = (size_t)row * DD + c;
    const float v = x[idx];
    // manual round-to-nearest-even fp32 -> bf16 (inputs are finite gaussians)
    unsigned int u = __float_as_uint(v);
    unsigned int r = (u + 0x7FFFu + ((u >> 16) & 1u)) >> 16;
    xb[idx] = (unsigned short)r;

    float p = v * v;
#pragma unroll
    for (int off = 32; off > 0; off >>= 1) p += __shfl_down(p, off, 64);
    __shared__ float wsum[4];
    const int wave = c >> 6, lane = c & 63;
    if (lane == 0) wsum[wave] = p;
    __syncthreads();
    if (c == 0) sq[row] = wsum[0] + wsum[1] + wsum[2] + wsum[3];
}

// ---------------- GEMM (X · X^T) + fused sigmoid-distance epilogue ----------------
// m97 structure: 128x128 block tile, 4 waves in 2x2, each wave 64x64 via 4x4 MFMA
// 16x16x32 bf16 tiles; BK=32; global_load_lds width=16 staging.
__global__ __launch_bounds__(256) void gemm_sig_kernel(
    const unsigned short* __restrict__ Xb, const float* __restrict__ sq,
    const float* __restrict__ thrp, const float* __restrict__ tp,
    float* __restrict__ out) {
    __shared__ __align__(16) unsigned short lA[128 * 32];
    __shared__ __align__(16) unsigned short lB[128 * 32];

    const int tid = threadIdx.x;
    const int wave = tid >> 6;
    const int lane = tid & 63;

    const int brow = blockIdx.y;
    const int bcol = blockIdx.x;
    const int wrow = (wave >> 1) * 64;
    const int wcol = (wave & 1) * 64;

    // staging: chunk = 16 rows of the [128][32] tile = 1024B; lane l covers
    // row chunk*16 + l/4, k-octet (l&3)*8  -> LDS contiguous in lane order.
    const int srow = lane >> 2;
    const int scol = (lane & 3) * 8;

    const size_t rowA0 = (size_t)brow * 128;
    const size_t rowB0 = (size_t)bcol * 128;

    f32x4 acc[4][4] = {};

    // fragment read indices (A-operand layout: m = lane&15, k = (lane>>4)*8 + j)
    const int fr = lane & 15;
    const int fk = (lane >> 4) * 8;

    for (int k0 = 0; k0 < DD; k0 += 32) {
        __syncthreads();  // LDS reuse guard
#pragma unroll
        for (int r = 0; r < 2; ++r) {
            const int chunk = wave * 2 + r;           // 0..7
            const int row = chunk * 16 + srow;        // 0..127
            const unsigned short* gA = Xb + (rowA0 + row) * DD + (k0 + scol);
            const unsigned short* gB = Xb + (rowB0 + row) * DD + (k0 + scol);
            __builtin_amdgcn_global_load_lds(
                (const __attribute__((address_space(1))) void*)gA,
                (__attribute__((address_space(3))) void*)(&lA[chunk * 512]), 16, 0, 0);
            __builtin_amdgcn_global_load_lds(
                (const __attribute__((address_space(1))) void*)gB,
                (__attribute__((address_space(3))) void*)(&lB[chunk * 512]), 16, 0, 0);
        }
        __syncthreads();  // drains vmcnt for global_load_lds

        bf16x8 af[4], bfv[4];
#pragma unroll
        for (int t = 0; t < 4; ++t) {
            af[t]  = *(const bf16x8*)&lA[(wrow + t * 16 + fr) * 32 + fk];
            bfv[t] = *(const bf16x8*)&lB[(wcol + t * 16 + fr) * 32 + fk];
        }
#pragma unroll
        for (int ti = 0; ti < 4; ++ti)
#pragma unroll
            for (int tj = 0; tj < 4; ++tj)
                acc[ti][tj] = __builtin_amdgcn_mfma_f32_16x16x32_bf16(
                    af[ti], bfv[tj], acc[ti][tj], 0, 0, 0);
    }

    // epilogue: dist2 = sq_i + sq_j - 2*dot; diag forced to 0; out = sigmoid(-(dist+thr)*t)
    const float thr = thrp[0];
    const float tv = tp[0];
    // C/D layout (16x16x32): col = lane&15, row = (lane>>4)*4 + reg
    const int c0 = lane & 15;
    const int r0 = (lane >> 4) * 4;

#pragma unroll
    for (int ti = 0; ti < 4; ++ti) {
#pragma unroll
        for (int tj = 0; tj < 4; ++tj) {
            const size_t gcol = rowB0 + wcol + tj * 16 + c0;
            const float sqj = sq[gcol];
            const size_t growb = rowA0 + wrow + ti * 16 + r0;
#pragma unroll
            for (int rg = 0; rg < 4; ++rg) {
                const size_t grow = growb + rg;
                float d2 = sq[grow] + sqj - 2.0f * acc[ti][tj][rg];
                if (grow == gcol) d2 = 0.0f;          // kill bf16 cancellation on diagonal
                d2 = fmaxf(d2, 1e-12f);
                const float dist = sqrtf(d2);
                const float diff = (dist + thr) * tv;
                out[grow * NN + gcol] = 1.0f / (1.0f + __expf(diff));
            }
        }
    }
}

extern "C" void kernel_launch(void* const* d_in, const int* in_sizes, int n_in,
                              void* d_out, int out_size, void* d_ws, size_t ws_size,
                              hipStream_t stream) {
    const float* x = (const float*)d_in[0];
    const float* threshold = (const float*)d_in[1];
    const float* t = (const float*)d_in[2];
    float* out = (float*)d_out;

    unsigned short* xb = (unsigned short*)d_ws;                       // 4 MB bf16 X
    float* sq = (float*)((char*)d_ws + (size_t)NN * DD * sizeof(unsigned short));

    prep_kernel<<<NN, 256, 0, stream>>>(x, xb, sq);
    dim3 grid(NN / 128, NN / 128);
    gemm_sig_kernel<<<grid, 256, 0, stream>>>(xb, sq, threshold, t, out);
}